// Round 3
// baseline (180.623 us; speedup 1.0000x reference)
//
#include <hip/hip_runtime.h>

// B=16, Lk=2048, Lq=256, DIM=512, HEADS=8, d_k=64 — f32 I/O, bf16 MFMA internally.
// out = softmax((G@Wq+bq) heads @ L^T * scale) @ L, merge heads, @ Wo + bo
#define KSTR 72   // attn P-buffer row stride (shorts)

typedef __attribute__((ext_vector_type(8))) short short8;  // 8 bf16 (4 VGPRs)
typedef __attribute__((ext_vector_type(4))) float f32x4;

#define EXP2F(x) __builtin_amdgcn_exp2f(x)

__device__ __forceinline__ unsigned short f2bf(float f) {   // RNE f32->bf16
    union { float f; unsigned u; } v; v.f = f;
    unsigned r = v.u + 0x7fff + ((v.u >> 16) & 1);
    return (unsigned short)(r >> 16);
}
__device__ __forceinline__ unsigned pk2(float a, float b) {
    return (unsigned)f2bf(a) | ((unsigned)f2bf(b) << 16);
}

// ---- W[512,512] f32 -> WF frag-order bf16: WF[kt][ntg][lane][8] with
// elem j = W[32kt+8quad+j][16ntg+c], lane=(quad<<4)|c. blockIdx.y picks matrix.
__global__ __launch_bounds__(256) void conv_W(const float* __restrict__ Wq,
                                              const float* __restrict__ Wo,
                                              unsigned short* __restrict__ WqF,
                                              unsigned short* __restrict__ WoF) {
    const float* W = blockIdx.y ? Wo : Wq;
    unsigned short* WF = blockIdx.y ? WoF : WqF;
    int g = blockIdx.x * 256 + threadIdx.x;       // [0, 32768)
    int lane = g & 63, ntg = (g >> 6) & 31, kt = g >> 11;
    int c = lane & 15, quad = lane >> 4;
    const float* wp = W + (size_t)(32 * kt + 8 * quad) * 512 + 16 * ntg + c;
    float v[8];
    #pragma unroll
    for (int j = 0; j < 8; j++) v[j] = wp[(size_t)j * 512];
    uint4 u;
    u.x = pk2(v[0], v[1]); u.y = pk2(v[2], v[3]);
    u.z = pk2(v[4], v[5]); u.w = pk2(v[6], v[7]);
    *(uint4*)(WF + (size_t)g * 8) = u;
}

// ---- L[16,2048,512] f32 -> KF + VF frag tensors (bf16), per (b,h,t) 64x64 tile.
__global__ __launch_bounds__(256) void conv_L(const float* __restrict__ Lmat,
                                              unsigned short* __restrict__ KF,
                                              unsigned short* __restrict__ VF) {
    __shared__ unsigned short KFs[4096];
    __shared__ unsigned short VFs[4096];
    const int blk = blockIdx.x;            // ((b*8+h)*32+t)
    const int t = blk & 31, h = (blk >> 5) & 7, b = blk >> 8;
    const int tid = threadIdx.x;
    const int key = tid & 63, wv = tid >> 6;   // 16 d's per thread

    const float* src = Lmat + ((size_t)(b * 2048 + 64 * t + key)) * 512 + 64 * h + 16 * wv;
    float4 a0 = *(const float4*)src;
    float4 a1 = *(const float4*)(src + 4);
    float4 a2 = *(const float4*)(src + 8);
    float4 a3 = *(const float4*)(src + 12);
    float vals[16] = {a0.x, a0.y, a0.z, a0.w, a1.x, a1.y, a1.z, a1.w,
                      a2.x, a2.y, a2.z, a2.w, a3.x, a3.y, a3.z, a3.w};
    #pragma unroll
    for (int i = 0; i < 16; i++) {
        int d = 16 * wv + i;
        unsigned short bv = f2bf(vals[i]);
        KFs[((((key >> 4) * 2 + (d >> 5)) * 64) + ((d >> 3) & 3) * 16 + (key & 15)) * 8 + (d & 7)] = bv;
        VFs[((((d >> 4) * 2 + (key >> 5)) * 64) + ((key >> 3) & 3) * 16 + (d & 15)) * 8 + (key & 7)] = bv;
    }
    __syncthreads();
    size_t gbase = (size_t)blk * 4096 + tid * 16;
    *(uint4*)(KF + gbase)     = *(const uint4*)&KFs[tid * 16];
    *(uint4*)(KF + gbase + 8) = *(const uint4*)&KFs[tid * 16 + 8];
    *(uint4*)(VF + gbase)     = *(const uint4*)&VFs[tid * 16];
    *(uint4*)(VF + gbase + 8) = *(const uint4*)&VFs[tid * 16 + 8];
}

// ---- barrier-free gemm: C[M,512] = (A@W + bias)*oscale. No LDS, no syncs.
template<bool A_BF16, bool OUT_BF16>
__global__ __launch_bounds__(256, 2) void gemm_direct(const void* __restrict__ Ap,
                                                      const unsigned short* __restrict__ WF,
                                                      const float* __restrict__ bias,
                                                      void* __restrict__ Cp,
                                                      float oscale) {
    const int tid = threadIdx.x;
    const int wv = tid >> 6, lane = tid & 63;
    const int c = lane & 15, quad = lane >> 4;
    const int m0 = blockIdx.x * 64, n0 = blockIdx.y * 64;
    const int row = m0 + 16 * wv + c;

    f32x4 acc[4];
    #pragma unroll
    for (int nt = 0; nt < 4; nt++) acc[nt] = (f32x4){0.f, 0.f, 0.f, 0.f};

    #pragma unroll
    for (int kk = 0; kk < 16; kk++) {
        short8 af;
        if (A_BF16) {
            af = *(const short8*)((const unsigned short*)Ap + (size_t)row * 512 + 32 * kk + 8 * quad);
        } else {
            const float* ap = (const float*)Ap + (size_t)row * 512 + 32 * kk + 8 * quad;
            float4 x0 = *(const float4*)ap;
            float4 x1 = *(const float4*)(ap + 4);
            af[0] = (short)f2bf(x0.x); af[1] = (short)f2bf(x0.y);
            af[2] = (short)f2bf(x0.z); af[3] = (short)f2bf(x0.w);
            af[4] = (short)f2bf(x1.x); af[5] = (short)f2bf(x1.y);
            af[6] = (short)f2bf(x1.z); af[7] = (short)f2bf(x1.w);
        }
        #pragma unroll
        for (int nt = 0; nt < 4; nt++) {
            short8 bf = *(const short8*)(WF +
                (((size_t)kk * 32 + (n0 >> 4) + nt) * 64 + lane) * 8);
            acc[nt] = __builtin_amdgcn_mfma_f32_16x16x32_bf16(af, bf, acc[nt], 0, 0, 0);
        }
    }

    #pragma unroll
    for (int nt = 0; nt < 4; nt++) {
        float bv = bias[n0 + 16 * nt + c];
        #pragma unroll
        for (int r = 0; r < 4; r++) {
            float v = (acc[nt][r] + bv) * oscale;
            size_t idx = (size_t)(m0 + 16 * wv + 4 * quad + r) * 512 + n0 + 16 * nt + c;
            if (OUT_BF16) ((unsigned short*)Cp)[idx] = f2bf(v);
            else          ((float*)Cp)[idx] = v;
        }
    }
}

#define GLD(dst, base, off) \
    asm volatile("global_load_dwordx4 %0, %1, off offset:" #off \
                 : "=v"(dst) : "v"(base) : "memory")
#define WAITV(n) asm volatile("s_waitcnt vmcnt(" #n ")" ::: "memory")
#define SCHEDB() __builtin_amdgcn_sched_barrier(0)

// ---- attn: two-stage cross-tile pipeline. Three load-scheduling variants all
// measured 42.5us -> K/V latency is NOT the bottleneck; the serial per-tile
// chain QK->exp->cvt->ds_write->ds_read->PV is. Double-buffered sacc + P-LDS
// let QK(t+1) MFMAs sit between P(t) writes and P(t) reads (covers the LDS
// round-trip), and exp VALU overlap in-flight loads. setprio(1) around MFMA
// clusters (T5, attn-positive).
__global__ __launch_bounds__(256, 2) void attn_frag(const unsigned short* __restrict__ Q,
                                                    const unsigned short* __restrict__ KF,
                                                    const unsigned short* __restrict__ VF,
                                                    unsigned short* __restrict__ X) {
    __shared__ unsigned short Pw[4][2][16 * KSTR];   // [wave][buf][...]

    // swizzle: raw = xcd + 8*(qt + 4*grp); bh = grp*8 + xcd -> b=grp, h=xcd
    const int raw = blockIdx.x;
    const int h  = raw & 7;
    const int qt = (raw >> 3) & 3;
    const int b  = raw >> 5;
    const int tid = threadIdx.x;
    const int wv = tid >> 6, lane = tid & 63;
    const int c = lane & 15, quad = lane >> 4;

    short8 qa[2];
    {
        const unsigned short* qsrc =
            Q + ((size_t)(b * 256 + qt * 64 + 16 * wv + c)) * 512 + h * 64;
        qa[0] = *(const short8*)(qsrc + 8 * quad);
        qa[1] = *(const short8*)(qsrc + 32 + 8 * quad);
    }
    WAITV(0); SCHEDB();   // drain Q loads -> in-loop vmcnt counts are exact

    short8 ones;
    #pragma unroll
    for (int i = 0; i < 8; i++) ones[i] = (short)0x3F80;

    f32x4 oacc[4];
    #pragma unroll
    for (int dt = 0; dt < 4; dt++) oacc[dt] = (f32x4){0.f, 0.f, 0.f, 0.f};
    f32x4 lacc = (f32x4){0.f, 0.f, 0.f, 0.f};

    const int swc = (c >> 3) & 1;
    const int swr = (quad >> 1) & 1;

    const unsigned short* kf = KF + ((size_t)((b * 8 + h) * 32)) * 4096 + lane * 8;
    const unsigned short* vf = VF + ((size_t)((b * 8 + h) * 32)) * 4096 + lane * 8;

    short8 kc[8], vc[8], kn[8], vn[8];
    f32x4 sA[4], sB[4];

#define ISSUE8(buf, bp, tp) do { \
        const unsigned short* p2_ = (bp) + (size_t)(tp) * 4096; \
        const unsigned short* p3_ = p2_ + 2048; \
        GLD(buf[0], p2_, 0);    GLD(buf[1], p2_, 1024); \
        GLD(buf[2], p2_, 2048); GLD(buf[3], p2_, 3072); \
        GLD(buf[4], p3_, 0);    GLD(buf[5], p3_, 1024); \
        GLD(buf[6], p3_, 2048); GLD(buf[7], p3_, 3072); \
    } while (0)

    // QK: S = qa x kb (8 MFMA), zero-init
    auto qk = [&](f32x4* S, short8* kb) {
        #pragma unroll
        for (int nt = 0; nt < 4; nt++) S[nt] = (f32x4){0.f, 0.f, 0.f, 0.f};
        __builtin_amdgcn_s_setprio(1);
        #pragma unroll
        for (int nt = 0; nt < 4; nt++)
            #pragma unroll
            for (int ks = 0; ks < 2; ks++)
                S[nt] = __builtin_amdgcn_mfma_f32_16x16x32_bf16(
                    qa[ks], kb[nt * 2 + ks], S[nt], 0, 0, 0);
        __builtin_amdgcn_s_setprio(0);
    };
    // exp2 + cvt + ds_write of S into P-buf
    auto store_p = [&](f32x4* S, int buf) {
        #pragma unroll
        for (int nt = 0; nt < 4; nt++)
            #pragma unroll
            for (int r = 0; r < 4; r++)
                Pw[wv][buf][(4 * quad + r) * KSTR + ((16 * nt + c) ^ (8 * swr))] =
                    f2bf(EXP2F(S[nt][r]));
    };
    // ds_read P + PV MFMAs (compiler inserts the lgkmcnt for its own ds ops)
    auto pv = [&](short8* vb, int buf) {
        short8 pa0 = *(const short8*)&Pw[wv][buf][c * KSTR + (8 * (quad ^ swc))];
        short8 pa1 = *(const short8*)&Pw[wv][buf][c * KSTR + 32 + (8 * (quad ^ swc))];
        __builtin_amdgcn_s_setprio(1);
        #pragma unroll
        for (int dt = 0; dt < 4; dt++) {
            oacc[dt] = __builtin_amdgcn_mfma_f32_16x16x32_bf16(pa0, vb[dt * 2], oacc[dt], 0, 0, 0);
            oacc[dt] = __builtin_amdgcn_mfma_f32_16x16x32_bf16(pa1, vb[dt * 2 + 1], oacc[dt], 0, 0, 0);
        }
        lacc = __builtin_amdgcn_mfma_f32_16x16x32_bf16(pa0, ones, lacc, 0, 0, 0);
        lacc = __builtin_amdgcn_mfma_f32_16x16x32_bf16(pa1, ones, lacc, 0, 0, 0);
        __builtin_amdgcn_s_setprio(0);
    };

    // tile body: scur holds S(t); knext holds K(t+1) loads; vcur = V(t);
    // vnext gets V(t+1) issue; kiss gets K(t+2) issue.
    auto body = [&](int t, f32x4* scur, f32x4* snext, short8* knext,
                    short8* vcur, short8* vnext, short8* kiss) {
        if (t + 1 < 32) ISSUE8(vnext, vf, t + 1);       // in flight: V(t),K(t+1),V(t+1)=24
        store_p(scur, t & 1);                           // load-independent VALU
        if (t + 1 < 32) {
            WAITV(8); SCHEDB();                         // retire V(t)+K(t+1); V(t+1) stays
            qk(snext, knext);                           // covers P write->read gap
        } else {
            WAITV(0); SCHEDB();                         // drain V(31)
        }
        pv(vcur, t & 1);
        if (t + 2 < 32) ISSUE8(kiss, kf, t + 2);        // back to 16 in flight
    };

    // prologue: K0 | V0 | K1 in flight; wait K0; S(0)
    ISSUE8(kc, kf, 0);
    ISSUE8(vc, vf, 0);
    ISSUE8(kn, kf, 1);
    WAITV(16); SCHEDB();
    qk(sA, kc);

    for (int t = 0; t < 32; t += 2) {
        body(t,     sA, sB, kn, vc, vn, kc);   // even: consume vc, K(t+2)->kc
        body(t + 1, sB, sA, kc, vn, vc, kn);   // odd:  consume vn, K(t+3)->kn
    }

    #pragma unroll
    for (int r = 0; r < 4; r++) {
        float inv = 1.f / lacc[r];
        size_t row = (size_t)(b * 256 + qt * 64 + 16 * wv + 4 * quad + r);
        unsigned short* xp = X + row * 512 + h * 64;
        #pragma unroll
        for (int dt = 0; dt < 4; dt++)
            xp[16 * dt + c] = f2bf(oacc[dt][r] * inv);
    }
#undef ISSUE8
}

// ---------------------------------------------------------------------------
extern "C" void kernel_launch(void* const* d_in, const int* in_sizes, int n_in,
                              void* d_out, int out_size, void* d_ws, size_t ws_size,
                              hipStream_t stream) {
    const float* Lmat = (const float*)d_in[0];  // [16,2048,512]
    const float* G    = (const float*)d_in[1];  // [16,256,512]
    const float* Wq   = (const float*)d_in[2];  // [512,512]
    const float* bq   = (const float*)d_in[3];  // [512]
    const float* Wo   = (const float*)d_in[4];  // [512,512]
    const float* bo   = (const float*)d_in[5];  // [512]
    float* out = (float*)d_out;                 // [16,256,512] f32

    const float SCe = 0.005524271728019903f * 1.4426950408889634f;  // scale*log2e
    dim3 gg(64, 8);

    // ws layout (bf16 elems): Qws 2M | Xws 2M | WqF 256K | WoF 256K | KF 16M | VF 16M
    unsigned short* Qws = (unsigned short*)d_ws;
    unsigned short* Xws = Qws + (size_t)2097152;
    unsigned short* WqF = Xws + (size_t)2097152;
    unsigned short* WoF = WqF + (size_t)262144;
    unsigned short* KF  = WoF + (size_t)262144;
    unsigned short* VF  = KF  + (size_t)16777216;

    conv_W<<<dim3(128, 2), 256, 0, stream>>>(Wq, Wo, WqF, WoF);
    conv_L<<<4096, 256, 0, stream>>>(Lmat, KF, VF);
    gemm_direct<false, true><<<gg, 256, 0, stream>>>(G, WqF, bq, Qws, SCe);
    attn_frag<<<512, 256, 0, stream>>>(Qws, KF, VF, Xws);
    gemm_direct<true, false><<<gg, 256, 0, stream>>>(Xws, WoF, bo, out, 1.0f);
}